// Round 1
// baseline (304.001 us; speedup 1.0000x reference)
//
#include <hip/hip_runtime.h>

#define BLOCK 256
#define GRID  2048
#define NGRAPH 8

// d_ws layout: float[0..7] = per-graph dots, float[8] = base (sum x^2 + t^2)

__global__ __launch_bounds__(BLOCK) void reduce_kernel(
    const float4* __restrict__ x4,
    const float4* __restrict__ t4,
    const int*    __restrict__ batch,
    float* __restrict__ g_acc,
    long long M /* = N*4 float4 elements */)
{
    __shared__ float s_dots[NGRAPH];
    __shared__ float s_base;
    const int tid = threadIdx.x;
    if (tid < NGRAPH) s_dots[tid] = 0.0f;
    if (tid == 0)     s_base = 0.0f;
    __syncthreads();

    const long long stride = (long long)gridDim.x * (long long)blockDim.x;
    const long long start  = (long long)blockIdx.x * blockDim.x + tid;
    // Pad the bound to a multiple of stride so every lane in a wave runs the
    // same number of iterations (keeps all 64 lanes active for shuffles).
    const long long M_pad = ((M + stride - 1) / stride) * stride;

    float base = 0.0f;

    for (long long e = start; e < M_pad; e += stride) {
        const bool valid = (e < M);
        float4 a = make_float4(0.f, 0.f, 0.f, 0.f);
        float4 c = make_float4(0.f, 0.f, 0.f, 0.f);
        int b = 0;
        if (valid) {
            a = x4[e];
            c = t4[e];
            b = batch[e >> 2];   // 4 float4 elements per row
        }
        base += a.x*a.x + a.y*a.y + a.z*a.z + a.w*a.w
              + c.x*c.x + c.y*c.y + c.z*c.z + c.w*c.w;
        float d = a.x*c.x + a.y*c.y + a.z*c.z + a.w*c.w;

        const int b0 = __builtin_amdgcn_readfirstlane(b);
        if (__all(b == b0)) {
            // wave-uniform graph id: butterfly reduce across 64 lanes
            for (int off = 32; off > 0; off >>= 1)
                d += __shfl_xor(d, off, 64);
            if ((tid & 63) == 0)
                atomicAdd(&s_dots[b0], d);
        } else {
            // segment boundary inside the wave (rare: ~8 total)
            atomicAdd(&s_dots[b], d);
        }
    }

    // block-reduce base: wave butterfly, then one LDS atomic per wave
    for (int off = 32; off > 0; off >>= 1)
        base += __shfl_xor(base, off, 64);
    if ((tid & 63) == 0)
        atomicAdd(&s_base, base);
    __syncthreads();

    if (tid < NGRAPH) atomicAdd(&g_acc[tid], s_dots[tid]);
    if (tid == 0)     atomicAdd(&g_acc[NGRAPH], s_base);
}

__global__ void finalize_kernel(const float* __restrict__ g_acc,
                                float* __restrict__ out)
{
    if (threadIdx.x == 0) {
        float s = 0.0f;
        #pragma unroll
        for (int i = 0; i < NGRAPH; ++i) s += fabsf(g_acc[i]);
        out[0] = g_acc[NGRAPH] - 2.0f * s;
    }
}

extern "C" void kernel_launch(void* const* d_in, const int* in_sizes, int n_in,
                              void* d_out, int out_size, void* d_ws, size_t ws_size,
                              hipStream_t stream) {
    const float* inp   = (const float*)d_in[0];
    const float* tgt   = (const float*)d_in[1];
    const int*   batch = (const int*)d_in[2];
    // d_in[3] is batch_size == 8 (compile-time NGRAPH)

    const long long Nrows = (long long)in_sizes[0] / 16;  // F = 16
    const long long M     = Nrows * 4;                    // float4 elements

    float* g_acc = (float*)d_ws;
    hipMemsetAsync(g_acc, 0, (NGRAPH + 1) * sizeof(float), stream);

    reduce_kernel<<<GRID, BLOCK, 0, stream>>>(
        (const float4*)inp, (const float4*)tgt, batch, g_acc, M);

    finalize_kernel<<<1, 64, 0, stream>>>(g_acc, (float*)d_out);
}